// Round 1
// baseline (271.758 us; speedup 1.0000x reference)
//
#include <hip/hip_runtime.h>
#include <math.h>

#define NTOK   16384
#define DDIM   2048
#define EDIM   128
#define HDIM   128
#define TOKT   32
#define KC     32
#define NCH    (DDIM / KC)   // 64 chunks of 32 k

typedef __attribute__((ext_vector_type(8))) _Float16 half8;
typedef __attribute__((ext_vector_type(4))) _Float16 half4;
typedef __attribute__((ext_vector_type(4))) float    f32x4;

// b32-granule XOR swizzle for epilogue A[32][128]: conflict-free row+column.
__device__ __forceinline__ int swz(int t, int e) {
  return t * EDIM + ((e & 96) | ((e ^ t) & 31));
}

// ---- W pre-convert: fragment-ordered f16 hi/lo planes in workspace ----
// frag idx -> (nt, ks, lane); lane holds B[k=ks*32+(lane>>4)*8+j][n=nt*16+(lane&15)]
// = Wr[n][k], scaled by 32 (hi) and 32*2048 (lo) to dodge f16 denormals.
__global__ __launch_bounds__(256)
void conv_w(const float* __restrict__ Wr,
            _Float16* __restrict__ wh, _Float16* __restrict__ wl) {
  const int idx  = (int)blockIdx.x * 256 + (int)threadIdx.x;  // 0..32767
  const int lane = idx & 63;
  const int ks   = (idx >> 6) & 63;
  const int nt   = idx >> 12;
  const int n    = nt * 16 + (lane & 15);
  const int k0   = ks * 32 + (lane >> 4) * 8;
  half8 h, l;
#pragma unroll
  for (int j = 0; j < 8; ++j) {
    const float w = Wr[(size_t)n * DDIM + k0 + j] * 32.0f;
    const _Float16 hh = (_Float16)w;
    h[j] = hh;
    l[j] = (_Float16)((w - (float)hh) * 2048.0f);
  }
  *(half8*)(wh + (size_t)idx * 8) = h;
  *(half8*)(wl + (size_t)idx * 8) = l;
}

__global__ __launch_bounds__(1024, 8)
void fused_router(const float* __restrict__ x,
                  const _Float16* __restrict__ wsh,
                  const _Float16* __restrict__ wsl,
                  const float* __restrict__ Wd,
                  const float* __restrict__ gamma,
                  const float* __restrict__ beta,
                  const float* __restrict__ rnn,
                  const float* __restrict__ gum,
                  float* __restrict__ outb,
                  float* __restrict__ outa) {
  // GEMM phase (halves index space xs):
  //   x bufs:  b*2048 + mt*512 + lane*8          hi; +1024 lo   (2 x 4 KB)
  //   W bufs:  4096 + b*8192 + nt*1024 + lane*8  hi; +512  lo   (2 x 16 KB)
  // Epilogue: A = bytes [0,16K), G4 = bytes [16K,32K)
  __shared__ char smraw[40960];
  _Float16* const xs = (_Float16*)smraw;
  float* const A  = (float*)smraw;
  float* const G4 = (float*)(smraw + 16384);

  const int tid  = (int)threadIdx.x;
  const int wv   = __builtin_amdgcn_readfirstlane(tid >> 6);  // 0..15
  const int lane = tid & 63;
  const int t0   = (int)blockIdx.x * TOKT;

  // MFMA mapping: wave = 1 m-tile x 1 n-tile, full K per wave.
  const int nt   = wv & 7;
  const int mt   = wv >> 3;
  const int quad = lane >> 4;
  const int col  = lane & 15;

  const int offA = mt * 512 + lane * 8;          // + b*2048 (+1024 lo)
  const int offB = 4096 + nt * 1024 + lane * 8;  // + b*8192 (+512 lo)

  // x staging: waves 0..3 (256 thr), thread -> (token, 4 consecutive k)
  const bool xstage = tid < 256;
  const int  sx_t   = tid >> 3;          // 0..31
  const int  sx_k8  = tid & 7;           // k-octant (4 k each)
  const float* xg   = x + (size_t)(t0 + sx_t) * DDIM + sx_k8 * 4;
  const int  sx_off = (sx_t >> 4) * 512 + (sx_k8 >> 1) * 128
                    + (sx_t & 15) * 8 + (sx_k8 & 1) * 4;     // halves, hi; +1024 lo

  // W staging: all 16 waves issue one global_load_lds each per chunk.
  // wave -> plane (wv>>3: 0=hi,1=lo) of n-tile (wv&7); 16 B/lane, LDS dest is
  // wave-uniform base + lane*16 (exactly the glds hardware layout).
  const int wnt = wv & 7;
  const int wpl = wv >> 3;
  const _Float16* wsrc = (wpl ? wsl : wsh) + (size_t)wnt * 32768 + (size_t)lane * 8;
  const int sw_off = 4096 + wnt * 1024 + wpl * 512;          // + b*8192

  f32x4 hh = {0,0,0,0}, cr = {0,0,0,0};

  // ---- preamble: stage chunk 0 into buffer 0 ----
  __builtin_amdgcn_global_load_lds(
      (const __attribute__((address_space(1))) void*)wsrc,
      (__attribute__((address_space(3))) void*)(xs + sw_off),
      16, 0, 0);
  if (xstage) {
    const float4 a = *(const float4*)xg;
    half4 h4, l4;
#pragma unroll
    for (int m = 0; m < 4; ++m) {
      const float v = (&a.x)[m];
      const _Float16 hv = (_Float16)v;
      h4[m] = hv; l4[m] = (_Float16)((v - (float)hv) * 2048.0f);
    }
    *(half4*)&xs[sx_off] = h4;
    *(half4*)&xs[1024 + sx_off] = l4;
  }

  float4 px;
#pragma unroll 2
  for (int c = 0; c < NCH; ++c) {
    __syncthreads();                      // buf (c&1) visible; buf (c&1)^1 free
    const int b  = c & 1;
    const int bn = b ^ 1;
    if (c + 1 < NCH) {                    // issue prefetch early (hide latency)
      __builtin_amdgcn_global_load_lds(
          (const __attribute__((address_space(1))) void*)(wsrc + (size_t)(c + 1) * 512),
          (__attribute__((address_space(3))) void*)(xs + bn * 8192 + sw_off),
          16, 0, 0);
      if (xstage) px = *(const float4*)(xg + (c + 1) * KC);
    }
    const half8 ah = *(const half8*)&xs[b * 2048 + offA];
    const half8 al = *(const half8*)&xs[b * 2048 + 1024 + offA];
    const half8 bh = *(const half8*)&xs[b * 8192 + offB];
    const half8 bl = *(const half8*)&xs[b * 8192 + offB + 512];

    hh = __builtin_amdgcn_mfma_f32_16x16x32_f16(ah, bh, hh, 0, 0, 0);
    cr = __builtin_amdgcn_mfma_f32_16x16x32_f16(ah, bl, cr, 0, 0, 0);
    cr = __builtin_amdgcn_mfma_f32_16x16x32_f16(al, bh, cr, 0, 0, 0);

    if (c + 1 < NCH && xstage) {          // convert + write into the free buffer
      half4 h4, l4;
#pragma unroll
      for (int m = 0; m < 4; ++m) {
        const float v = (&px.x)[m];
        const _Float16 hv = (_Float16)v;
        h4[m] = hv; l4[m] = (_Float16)((v - (float)hv) * 2048.0f);
      }
      *(half4*)&xs[bn * 2048 + sx_off] = h4;
      *(half4*)&xs[bn * 2048 + 1024 + sx_off] = l4;
    }
  }
  __syncthreads();                        // GEMM LDS dead

  // ---- unscale, add rnn, write emb to A (C/D: col=lane&15, row=quad*4+r) ----
  {
    const int e  = nt * 16 + col;
    const float rv = rnn[e];
#pragma unroll
    for (int r = 0; r < 4; ++r)
      A[swz(mt * 16 + quad * 4 + r, e)] =
          hh[r] * (1.0f / 32.0f) + cr[r] * (1.0f / 65536.0f) + rv;
  }
  __syncthreads();

  // ---- LayerNorm + exact GELU: 2 tokens per wave; G -> G4 (float4-swizzled) ----
  const int e0 = wv * 8;                  // decoder e-mapping
  {
    const float gm0 = gamma[lane], gm1 = gamma[lane + 64];
    const float bt0 = beta[lane],  bt1 = beta[lane + 64];
    for (int tt = wv * 2; tt < wv * 2 + 2; ++tt) {
      const float v0 = A[swz(tt, lane)];
      const float v1 = A[swz(tt, lane + 64)];
      float s = v0 + v1;
#pragma unroll
      for (int m = 32; m; m >>= 1) s += __shfl_xor(s, m);
      const float mu = s * (1.0f / 128.0f);
      const float d0 = v0 - mu, d1 = v1 - mu;
      float q = d0 * d0 + d1 * d1;
#pragma unroll
      for (int m = 32; m; m >>= 1) q += __shfl_xor(q, m);
      const float rstd = 1.0f / sqrtf(q * (1.0f / 128.0f) + 1e-5f);
      const float h0v = d0 * rstd * gm0 + bt0;
      const float h1v = d1 * rstd * gm1 + bt1;
      const float g0 = 0.5f * h0v * (1.0f + erff(h0v * 0.70710678118654752f));
      const float g1 = 0.5f * h1v * (1.0f + erff(h1v * 0.70710678118654752f));
      G4[(tt * 32 + ((lane >> 2) ^ tt)) * 4 + (lane & 3)] = g0;
      G4[(tt * 32 + ((((lane + 64) >> 2)) ^ tt)) * 4 + ((lane + 64) & 3)] = g1;
    }
  }
  __syncthreads();

  // ---- decoder GEMM: wave = 8 h-rows x 32 tokens; lane halves split rows ----
  {
    float acc2[4] = {0.0f, 0.0f, 0.0f, 0.0f};
    const int tokn  = lane & 31;
    const int rbase = e0 + (lane >> 5) * 4;
    const float4* wd4 = (const float4*)(Wd + (size_t)rbase * EDIM);
#pragma unroll 2
    for (int kg = 0; kg < EDIM / 4; ++kg) {
      const float4 gv = *(const float4*)&G4[(tokn * 32 + (kg ^ tokn)) * 4];
#pragma unroll
      for (int j = 0; j < 4; ++j) {
        const float4 w = wd4[(size_t)j * (EDIM / 4) + kg];
        acc2[j] = fmaf(gv.x, w.x,
                  fmaf(gv.y, w.y,
                  fmaf(gv.z, w.z,
                  fmaf(gv.w, w.w, acc2[j]))));
      }
    }
    // G4 and A are disjoint LDS regions; no barrier needed before A writes.
#pragma unroll
    for (int j = 0; j < 4; ++j) A[swz(tokn, rbase + j)] = acc2[j];
  }
  __syncthreads();

  // ---- gumbel-sigmoid, exact top-k (value then lower-index), output ----
  for (int tt = wv * 2; tt < wv * 2 + 2; ++tt) {
    const size_t T = (size_t)(t0 + tt);
    const float l0 = A[swz(tt, lane)];
    const float l1 = A[swz(tt, lane + 64)];
    const float gn0 = gum[T * HDIM + lane];
    const float gn1 = gum[T * HDIM + lane + 64];
    const float z0 = (l0 + gn0 + 3.0f) * 2.5f;
    const float z1 = (l1 + gn1 + 3.0f) * 2.5f;
    const float ba0 = 1.0f / (1.0f + expf(-z0));
    const float ba1 = 1.0f / (1.0f + expf(-z1));
    const unsigned ub0 = __float_as_uint(ba0);   // ba in (0,1]: bits monotone
    const unsigned ub1 = __float_as_uint(ba1);
    const int r0 = ba0 > 0.5f;                   // round: 0.5 -> 0
    const int r1 = ba1 > 0.5f;
    const int cnt = __popcll(__ballot(r0)) + __popcll(__ballot(r1));
    float bin0, bin1;
    if (cnt > 32) {
      unsigned v = 0u;                            // radix-select 32nd largest
#pragma unroll
      for (int b = 29; b >= 0; --b) {
        const unsigned cand = v | (1u << b);
        const int cc = __popcll(__ballot(ub0 >= cand)) + __popcll(__ballot(ub1 >= cand));
        if (cc >= 32) v = cand;
      }
      const int cgt = __popcll(__ballot(ub0 > v)) + __popcll(__ballot(ub1 > v));
      const int r = 32 - cgt;                     // tied slots; lower index wins
      const unsigned long long t0b = __ballot(ub0 == v);
      const unsigned long long t1b = __ballot(ub1 == v);
      const int n0 = __popcll(t0b);
      const unsigned long long mlt = (1ull << lane) - 1ull;
      const int rk0 = __popcll(t0b & mlt);
      const int rk1 = n0 + __popcll(t1b & mlt);
      bin0 = (ub0 > v || (ub0 == v && rk0 < r)) ? 1.0f : 0.0f;
      bin1 = (ub1 > v || (ub1 == v && rk1 < r)) ? 1.0f : 0.0f;
    } else if (cnt == 0) {
      float m = fmaxf(ba0, ba1);
#pragma unroll
      for (int mm = 32; mm; mm >>= 1) m = fmaxf(m, __shfl_xor(m, mm));
      const unsigned long long e0b = __ballot(ba0 == m);
      const unsigned long long e1b = __ballot(ba1 == m);
      const int hstar = e0b ? (__ffsll((unsigned long long)e0b) - 1)
                            : (64 + __ffsll((unsigned long long)e1b) - 1);
      bin0 = (lane == hstar) ? 1.0f : 0.0f;
      bin1 = (lane + 64 == hstar) ? 1.0f : 0.0f;
    } else {
      bin0 = r0 ? 1.0f : 0.0f;
      bin1 = r1 ? 1.0f : 0.0f;
    }
    outb[T * HDIM + lane]      = bin0;
    outb[T * HDIM + lane + 64] = bin1;
    outa[T * HDIM + lane]      = ba0;
    outa[T * HDIM + lane + 64] = ba1;
  }
}

extern "C" void kernel_launch(void* const* d_in, const int* in_sizes, int n_in,
                              void* d_out, int out_size, void* d_ws, size_t ws_size,
                              hipStream_t stream) {
  (void)in_sizes; (void)n_in; (void)ws_size; (void)out_size;
  const float* x   = (const float*)d_in[0];
  const float* Wr  = (const float*)d_in[1];
  const float* Wd  = (const float*)d_in[2];
  const float* gm  = (const float*)d_in[3];
  const float* bt  = (const float*)d_in[4];
  const float* rnn = (const float*)d_in[5];
  const float* gum = (const float*)d_in[6];
  float* outb = (float*)d_out;
  float* outa = outb + (size_t)NTOK * HDIM;   // tuple: (binary, binary_approx)

  _Float16* wh = (_Float16*)d_ws;             // 512 KB
  _Float16* wl = wh + (size_t)EDIM * DDIM;    // 512 KB

  conv_w<<<dim3(128), dim3(256), 0, stream>>>(Wr, wh, wl);
  fused_router<<<dim3(NTOK / TOKT), dim3(1024), 0, stream>>>(
      x, wh, wl, Wd, gm, bt, rnn, gum, outb, outa);
}